// Round 1
// baseline (410.341 us; speedup 1.0000x reference)
//
#include <hip/hip_runtime.h>
#include <hip/hip_bf16.h>

// QuantizedLinear: out[64,8192] = x[64,8192] @ (alpha * ternary(W))^T + bias
// W is [O=8192, I=8192] fp32 row-major (contiguous in I=K) -> B^T GEMM shape.
// Ternary {-1,0,+1} exact in bf16; alpha applied fp32 in epilogue; only x is
// rounded to bf16 (error ~0.3 vs threshold 3.94).

typedef __attribute__((ext_vector_type(8))) short short8;   // 8 bf16 = 4 VGPRs
typedef __attribute__((ext_vector_type(4))) float floatx4;  // MFMA acc

#define B_DIM 64
#define K_DIM 8192
#define O_DIM 8192
#define BN 64
#define BK 64
#define KSPLIT 8
#define KCHUNK (K_DIM / KSPLIT)   // 1024
#define KSTEPS (KCHUNK / BK)      // 16
#define LDSS 72                   // padded LDS row stride (bf16 elems) = 144 B, 16B-aligned

// ---- prep: x fp32 -> bf16 workspace; out = bias broadcast (re-done every call) ----
__global__ __launch_bounds__(256) void prep_kernel(
    const float* __restrict__ x, const float* __restrict__ bias,
    __hip_bfloat16* __restrict__ xbf, float* __restrict__ out) {
  int idx = blockIdx.x * 256 + threadIdx.x;          // 0 .. 524287 (B*K == B*O)
  xbf[idx] = __float2bfloat16(x[idx]);
  out[idx] = bias[idx & (O_DIM - 1)];
}

// ---- main GEMM: 1024 blocks (128 n-tiles x 8 k-slices), 256 threads ----
__global__ __launch_bounds__(256, 4) void gemm_kernel(
    const float* __restrict__ w, const unsigned short* __restrict__ xbf,
    const float* __restrict__ alpha, float* __restrict__ out) {
  __shared__ __align__(16) short Ws[BN * LDSS];
  __shared__ __align__(16) short Xs[B_DIM * LDSS];

  const int tid = threadIdx.x;
  const int nt = blockIdx.x & 127;   // n-tile (fast dim -> co-resident blocks share k-chunk for X L2 reuse)
  const int ks = blockIdx.x >> 7;    // k-slice 0..7
  const int n0 = nt * BN;
  const int k0 = ks * KCHUNK;

  // staging map: 4 threads per row, each covers 16 contiguous k
  const int srow = tid >> 2;                 // 0..63
  const int skb  = (tid & 3) << 4;           // 0,16,32,48

  const float* wp = w + (size_t)(n0 + srow) * K_DIM + (size_t)(k0 + skb);
  const unsigned short* xp = xbf + (size_t)srow * K_DIM + (size_t)(k0 + skb);
  const float thr = 0.5f * (alpha[n0 + srow] + 1e-8f);  // |w| > 0.5*(alpha+eps) -> +/-1

  // compute map
  const int wv  = tid >> 6;    // wave 0..3 -> n-sub tile
  const int ln  = tid & 63;
  const int lhi = ln >> 4;     // 0..3
  const int llo = ln & 15;

  floatx4 acc[4];
#pragma unroll
  for (int i = 0; i < 4; ++i) acc[i] = (floatx4){0.f, 0.f, 0.f, 0.f};

  float4 wa, wb, wc, wd;   // 16 raw W floats held across pipeline stage
  short8 xv0, xv1;         // 16 bf16 x values

  auto load_tile = [&](int kt) {
    const float* p = wp + kt * BK;
    wa = *(const float4*)(p);
    wb = *(const float4*)(p + 4);
    wc = *(const float4*)(p + 8);
    wd = *(const float4*)(p + 12);
    const unsigned short* q = xp + kt * BK;
    xv0 = *(const short8*)(const void*)(q);
    xv1 = *(const short8*)(const void*)(q + 8);
  };

  auto tern = [&](float v) -> short {
    // +1 -> 0x3F80, -1 -> 0xBF80, 0 -> 0 (bf16 bit patterns; two cmps + selects)
    return v > thr ? (short)0x3F80
                   : (v < -thr ? (short)(unsigned short)0xBF80 : (short)0);
  };

  auto store_tile = [&]() {
    short8 p0, p1;
    p0[0] = tern(wa.x); p0[1] = tern(wa.y); p0[2] = tern(wa.z); p0[3] = tern(wa.w);
    p0[4] = tern(wb.x); p0[5] = tern(wb.y); p0[6] = tern(wb.z); p0[7] = tern(wb.w);
    p1[0] = tern(wc.x); p1[1] = tern(wc.y); p1[2] = tern(wc.z); p1[3] = tern(wc.w);
    p1[4] = tern(wd.x); p1[5] = tern(wd.y); p1[6] = tern(wd.z); p1[7] = tern(wd.w);
    *(short8*)&Ws[srow * LDSS + skb]     = p0;
    *(short8*)&Ws[srow * LDSS + skb + 8] = p1;
    *(short8*)&Xs[srow * LDSS + skb]     = xv0;
    *(short8*)&Xs[srow * LDSS + skb + 8] = xv1;
  };

  auto compute = [&]() {
#pragma unroll
    for (int kk = 0; kk < 2; ++kk) {
      const int koff = kk * 32 + lhi * 8;
      short8 bfrag = *(const short8*)&Ws[(wv * 16 + llo) * LDSS + koff];
#pragma unroll
      for (int mt = 0; mt < 4; ++mt) {
        short8 afrag = *(const short8*)&Xs[(mt * 16 + llo) * LDSS + koff];
        acc[mt] = __builtin_amdgcn_mfma_f32_16x16x32_bf16(afrag, bfrag, acc[mt], 0, 0, 0);
      }
    }
  };

  load_tile(0);
  for (int kt = 0; kt < KSTEPS; ++kt) {
    __syncthreads();                      // prior compute done reading LDS
    store_tile();
    __syncthreads();
    if (kt + 1 < KSTEPS) load_tile(kt + 1);  // HBM loads in flight during compute
    compute();
  }

  // epilogue: C/D layout col=lane&15 (n), row=(lane>>4)*4+reg (m); scale by fp32 alpha
  const int ncol = n0 + wv * 16 + llo;
  const float av = alpha[ncol];
#pragma unroll
  for (int mt = 0; mt < 4; ++mt) {
    const int m = mt * 16 + lhi * 4;
#pragma unroll
    for (int r = 0; r < 4; ++r) {
      atomicAdd(&out[(size_t)(m + r) * O_DIM + ncol], acc[mt][r] * av);
    }
  }
}

extern "C" void kernel_launch(void* const* d_in, const int* in_sizes, int n_in,
                              void* d_out, int out_size, void* d_ws, size_t ws_size,
                              hipStream_t stream) {
  const float* x     = (const float*)d_in[0];  // [64, 8192]
  const float* w     = (const float*)d_in[1];  // [8192, 8192]
  const float* alpha = (const float*)d_in[2];  // [8192, 1]
  const float* bias  = (const float*)d_in[3];  // [8192]
  float* out = (float*)d_out;                  // [64, 8192]
  __hip_bfloat16* xbf = (__hip_bfloat16*)d_ws; // 1 MB scratch

  prep_kernel<<<(B_DIM * K_DIM) / 256, 256, 0, stream>>>(x, bias, xbf, out);
  gemm_kernel<<<(O_DIM / BN) * KSPLIT, 256, 0, stream>>>(
      w, (const unsigned short*)xbf, alpha, out);
}